// Round 1
// baseline (610.105 us; speedup 1.0000x reference)
//
#include <hip/hip_runtime.h>

#define N_NODES 20000
#define FDIM    256
#define NE      400000
#define NH      4
#define NC      64
#define NK      3
#define NEG_SLOPE 0.2f

// Virtual edge stream: [hop0 real E][hop0 self-loops N][hop1 E][hop2 E]
#define TOT_EDGES (3 * NE + N_NODES)
#define BASE0 0
#define BASE1 (NE + N_NODES)
#define BASE2 (2 * NE + N_NODES)

// ---------------------------------------------------------------------------
// GEMM: Y[N,512] = x[N,256] @ [Wl | Wr] + [bl | br]   (fp32, 64x64x16 tiles)
// ---------------------------------------------------------------------------
__global__ __launch_bounds__(256) void gemm_xlr(
    const float* __restrict__ x, const float* __restrict__ Wl,
    const float* __restrict__ Wr, const float* __restrict__ bl,
    const float* __restrict__ br, float* __restrict__ Y)
{
    __shared__ float As[16][64];   // [k][m]
    __shared__ float Bs[16][64];   // [k][n]
    const int row0 = blockIdx.x * 64;
    const int col0 = blockIdx.y * 64;
    const float* B    = (col0 < 256) ? Wl : Wr;
    const float* bias = (col0 < 256) ? bl : br;
    const int bcol0   = (col0 < 256) ? col0 : (col0 - 256);

    const int t  = threadIdx.x;
    const int tm = t >> 4;          // 0..15
    const int tn = t & 15;          // 0..15
    const int ar = t >> 2;          // 0..63  (A row within tile)
    const int ac = (t & 3) << 2;    // 0,4,8,12
    const int brr = t >> 4;         // 0..15  (B row within tile)
    const int bcc = (t & 15) << 2;  // 0..60

    float acc[4][4] = {};

    for (int k0 = 0; k0 < FDIM; k0 += 16) {
        float4 av = {0.f, 0.f, 0.f, 0.f};
        if (row0 + ar < N_NODES)
            av = *(const float4*)(x + (size_t)(row0 + ar) * FDIM + k0 + ac);
        As[ac + 0][ar] = av.x;
        As[ac + 1][ar] = av.y;
        As[ac + 2][ar] = av.z;
        As[ac + 3][ar] = av.w;
        *(float4*)&Bs[brr][bcc] =
            *(const float4*)(B + (size_t)(k0 + brr) * 256 + bcol0 + bcc);
        __syncthreads();
#pragma unroll
        for (int k = 0; k < 16; ++k) {
            float4 a = *(const float4*)&As[k][tm << 2];
            float4 b = *(const float4*)&Bs[k][tn << 2];
            acc[0][0] += a.x * b.x; acc[0][1] += a.x * b.y;
            acc[0][2] += a.x * b.z; acc[0][3] += a.x * b.w;
            acc[1][0] += a.y * b.x; acc[1][1] += a.y * b.y;
            acc[1][2] += a.y * b.z; acc[1][3] += a.y * b.w;
            acc[2][0] += a.z * b.x; acc[2][1] += a.z * b.y;
            acc[2][2] += a.z * b.z; acc[2][3] += a.z * b.w;
            acc[3][0] += a.w * b.x; acc[3][1] += a.w * b.y;
            acc[3][2] += a.w * b.z; acc[3][3] += a.w * b.w;
        }
        __syncthreads();
    }

    const int cb = tn << 2;
#pragma unroll
    for (int i = 0; i < 4; ++i) {
        int r = row0 + (tm << 2) + i;
        if (r < N_NODES) {
            float4 o;
            o.x = acc[i][0] + bias[bcol0 + cb + 0];
            o.y = acc[i][1] + bias[bcol0 + cb + 1];
            o.z = acc[i][2] + bias[bcol0 + cb + 2];
            o.w = acc[i][3] + bias[bcol0 + cb + 3];
            *(float4*)&Y[(size_t)r * 512 + col0 + cb] = o;
        }
    }
}

// ---------------------------------------------------------------------------
// CSR build: histogram -> scan (per hop) -> scatter
// ---------------------------------------------------------------------------
__device__ __forceinline__ void decode_edge(int i, const int* e0, const int* e1,
                                            const int* e2, int& k, int& src,
                                            int& dst)
{
    if (i < NE) {
        k = 0; src = e0[i]; dst = e0[NE + i];
    } else if (i < NE + N_NODES) {
        k = 0; src = i - NE; dst = src;          // hop-0 self loop
    } else if (i < 2 * NE + N_NODES) {
        int j = i - (NE + N_NODES);
        k = 1; src = e1[j]; dst = e1[NE + j];
    } else {
        int j = i - (2 * NE + N_NODES);
        k = 2; src = e2[j]; dst = e2[NE + j];
    }
}

__global__ void hist_kernel(const int* __restrict__ e0,
                            const int* __restrict__ e1,
                            const int* __restrict__ e2, int* __restrict__ cnt)
{
    for (int i = blockIdx.x * blockDim.x + threadIdx.x; i < TOT_EDGES;
         i += gridDim.x * blockDim.x) {
        int k, src, dst;
        decode_edge(i, e0, e1, e2, k, src, dst);
        atomicAdd(&cnt[k * N_NODES + dst], 1);
    }
}

// one block per hop; chunked Hillis-Steele scan over N_NODES counts
__global__ __launch_bounds__(1024) void scan_kernel(const int* __restrict__ cnt,
                                                    int* __restrict__ off,
                                                    int* __restrict__ cursor)
{
    const int k = blockIdx.x;
    const int* c = cnt + k * N_NODES;
    int* o   = off + (size_t)k * (N_NODES + 1);
    int* cur = cursor + k * N_NODES;
    __shared__ int sdata[1024];
    __shared__ int carry;
    if (threadIdx.x == 0) carry = 0;
    __syncthreads();
    for (int base = 0; base < N_NODES; base += 1024) {
        int i = base + threadIdx.x;
        int v = (i < N_NODES) ? c[i] : 0;
        sdata[threadIdx.x] = v;
        __syncthreads();
#pragma unroll
        for (int s = 1; s < 1024; s <<= 1) {
            int t2 = (threadIdx.x >= s) ? sdata[threadIdx.x - s] : 0;
            __syncthreads();
            sdata[threadIdx.x] += t2;
            __syncthreads();
        }
        int excl = sdata[threadIdx.x] - v;
        if (i < N_NODES) {
            int val = carry + excl;
            o[i]   = val;
            cur[i] = val;
        }
        __syncthreads();
        if (threadIdx.x == 1023) carry += sdata[1023];
        __syncthreads();
    }
    if (threadIdx.x == 0) o[N_NODES] = carry;
}

__global__ void scatter_kernel(const int* __restrict__ e0,
                               const int* __restrict__ e1,
                               const int* __restrict__ e2,
                               int* __restrict__ cursor,
                               int* __restrict__ srcs)
{
    for (int i = blockIdx.x * blockDim.x + threadIdx.x; i < TOT_EDGES;
         i += gridDim.x * blockDim.x) {
        int k, src, dst;
        decode_edge(i, e0, e1, e2, k, src, dst);
        int pos = atomicAdd(&cursor[k * N_NODES + dst], 1);
        int base = (k == 0) ? BASE0 : (k == 1) ? BASE1 : BASE2;
        srcs[base + pos] = src;
    }
}

// ---------------------------------------------------------------------------
// Aggregation: one wave per destination node; lane = channel (C == 64).
// Online softmax per head over in-edges; gating softmax inline; single write.
// ---------------------------------------------------------------------------
__device__ __forceinline__ void wave_reduce4(float& p0, float& p1, float& p2,
                                             float& p3)
{
#pragma unroll
    for (int s = 32; s >= 1; s >>= 1) {
        p0 += __shfl_xor(p0, s);
        p1 += __shfl_xor(p1, s);
        p2 += __shfl_xor(p2, s);
        p3 += __shfl_xor(p3, s);
    }
}

__global__ __launch_bounds__(256) void aggregate_kernel(
    const float* __restrict__ XLR,      // [N,512] = [xl | xr]
    const float* __restrict__ x,        // [N,256]
    const int* __restrict__ off,        // [3][N+1]
    const int* __restrict__ srcs,       // [TOT_EDGES]
    const float* __restrict__ att,      // [3,4,64]
    const float* __restrict__ bias_out, // [3,64]
    const float* __restrict__ Wg,       // [256,3]
    const float* __restrict__ bg,       // [3]
    float* __restrict__ out)            // [N,64]
{
    const int wid  = (blockIdx.x * blockDim.x + threadIdx.x) >> 6;
    const int lane = threadIdx.x & 63;
    if (wid >= N_NODES) return;
    const int n = wid;

    // ---- gating weights: softmax(x[n] @ Wg + bg) ----
    float w0, w1, w2;
    {
        float p0 = 0.f, p1 = 0.f, p2 = 0.f, p3 = 0.f;
        const float* xrow = x + (size_t)n * FDIM;
#pragma unroll
        for (int q = 0; q < 4; ++q) {
            int f = q * 64 + lane;
            float xv = xrow[f];
            p0 += xv * Wg[f * 3 + 0];
            p1 += xv * Wg[f * 3 + 1];
            p2 += xv * Wg[f * 3 + 2];
        }
        wave_reduce4(p0, p1, p2, p3);
        float g0 = p0 + bg[0], g1 = p1 + bg[1], g2 = p2 + bg[2];
        float mg = fmaxf(g0, fmaxf(g1, g2));
        g0 = __expf(g0 - mg); g1 = __expf(g1 - mg); g2 = __expf(g2 - mg);
        float inv = 1.f / (g0 + g1 + g2);
        w0 = g0 * inv; w1 = g1 * inv; w2 = g2 * inv;
    }
    const float wk[3] = {w0, w1, w2};

    // ---- xr row (stays in registers across hops) ----
    const float* xrr = XLR + (size_t)n * 512 + 256;
    const float xr0 = xrr[lane];
    const float xr1 = xrr[64 + lane];
    const float xr2 = xrr[128 + lane];
    const float xr3 = xrr[192 + lane];

    float o_acc = 0.f;

#pragma unroll
    for (int k = 0; k < NK; ++k) {
        const float a0 = att[(k * 4 + 0) * 64 + lane];
        const float a1 = att[(k * 4 + 1) * 64 + lane];
        const float a2 = att[(k * 4 + 2) * 64 + lane];
        const float a3 = att[(k * 4 + 3) * 64 + lane];
        const int jb = off[k * (N_NODES + 1) + n];
        const int je = off[k * (N_NODES + 1) + n + 1];
        const int base = (k == 0) ? BASE0 : (k == 1) ? BASE1 : BASE2;

        float m0 = -1e30f, m1 = -1e30f, m2 = -1e30f, m3 = -1e30f;
        float l0 = 0.f, l1 = 0.f, l2 = 0.f, l3 = 0.f;
        float c0 = 0.f, c1 = 0.f, c2 = 0.f, c3 = 0.f;

        for (int j = jb; j < je; ++j) {
            int src = srcs[base + j];
            const float* xlrow = XLR + (size_t)src * 512;
            float v0 = xlrow[lane];
            float v1 = xlrow[64 + lane];
            float v2 = xlrow[128 + lane];
            float v3 = xlrow[192 + lane];

            float e0 = v0 + xr0; e0 = (e0 > 0.f) ? e0 : NEG_SLOPE * e0;
            float e1 = v1 + xr1; e1 = (e1 > 0.f) ? e1 : NEG_SLOPE * e1;
            float e2 = v2 + xr2; e2 = (e2 > 0.f) ? e2 : NEG_SLOPE * e2;
            float e3 = v3 + xr3; e3 = (e3 > 0.f) ? e3 : NEG_SLOPE * e3;

            float p0 = e0 * a0, p1 = e1 * a1, p2 = e2 * a2, p3 = e3 * a3;
            wave_reduce4(p0, p1, p2, p3);   // p_h = s[e,h] on every lane

            // online softmax update, head 0..3
            float nm, sc, ee;
            nm = fmaxf(m0, p0); sc = __expf(m0 - nm); ee = __expf(p0 - nm);
            l0 = l0 * sc + ee; c0 = c0 * sc + ee * v0; m0 = nm;
            nm = fmaxf(m1, p1); sc = __expf(m1 - nm); ee = __expf(p1 - nm);
            l1 = l1 * sc + ee; c1 = c1 * sc + ee * v1; m1 = nm;
            nm = fmaxf(m2, p2); sc = __expf(m2 - nm); ee = __expf(p2 - nm);
            l2 = l2 * sc + ee; c2 = c2 * sc + ee * v2; m2 = nm;
            nm = fmaxf(m3, p3); sc = __expf(m3 - nm); ee = __expf(p3 - nm);
            l3 = l3 * sc + ee; c3 = c3 * sc + ee * v3; m3 = nm;
        }

        float msg = 0.f;
        if (je > jb)
            msg = 0.25f * (c0 / l0 + c1 / l1 + c2 / l2 + c3 / l3);
        o_acc += wk[k] * (msg + bias_out[k * 64 + lane]);
    }

    out[(size_t)n * 64 + lane] = o_acc;
}

// ---------------------------------------------------------------------------
extern "C" void kernel_launch(void* const* d_in, const int* in_sizes, int n_in,
                              void* d_out, int out_size, void* d_ws,
                              size_t ws_size, hipStream_t stream)
{
    const float* x        = (const float*)d_in[0];
    const int*   e0       = (const int*)d_in[1];
    const int*   e1       = (const int*)d_in[2];
    const int*   e2       = (const int*)d_in[3];
    const float* Wl       = (const float*)d_in[4];
    const float* bl       = (const float*)d_in[5];
    const float* Wr       = (const float*)d_in[6];
    const float* br       = (const float*)d_in[7];
    const float* att      = (const float*)d_in[8];
    const float* bias_out = (const float*)d_in[9];
    const float* Wg       = (const float*)d_in[10];
    const float* bg       = (const float*)d_in[11];
    float* out = (float*)d_out;

    char* wsb = (char*)d_ws;
    float* XLR = (float*)wsb;                       // N*512 f32
    size_t o = (size_t)N_NODES * 512 * sizeof(float);
    int* cnt    = (int*)(wsb + o); o += (size_t)3 * N_NODES * sizeof(int);
    int* off    = (int*)(wsb + o); o += (size_t)3 * (N_NODES + 1) * sizeof(int);
    int* cursor = (int*)(wsb + o); o += (size_t)3 * N_NODES * sizeof(int);
    int* srcs   = (int*)(wsb + o); o += (size_t)TOT_EDGES * sizeof(int);

    hipMemsetAsync(cnt, 0, (size_t)3 * N_NODES * sizeof(int), stream);

    dim3 ggrid((N_NODES + 63) / 64, 8);
    gemm_xlr<<<ggrid, 256, 0, stream>>>(x, Wl, Wr, bl, br, XLR);

    int eblocks = (TOT_EDGES + 255) / 256;
    hist_kernel<<<eblocks, 256, 0, stream>>>(e0, e1, e2, cnt);
    scan_kernel<<<3, 1024, 0, stream>>>(cnt, off, cursor);
    scatter_kernel<<<eblocks, 256, 0, stream>>>(e0, e1, e2, cursor, srcs);

    int ablocks = (N_NODES * 64 + 255) / 256;
    aggregate_kernel<<<ablocks, 256, 0, stream>>>(XLR, x, off, srcs, att,
                                                  bias_out, Wg, bg, out);
}

// Round 2
// 457.869 us; speedup vs baseline: 1.3325x; 1.3325x over previous
//
#include <hip/hip_runtime.h>

#define N_NODES 20000
#define FDIM    256
#define NE      400000
#define NH      4
#define NC      64
#define NK      3
#define NEG_SLOPE 0.2f
#define LOG2E   1.44269504088896340736f

// Virtual edge stream: [hop0 real E][hop0 self-loops N][hop1 E][hop2 E]
#define TOT_EDGES (3 * NE + N_NODES)
#define BASE0 0
#define BASE1 (NE + N_NODES)
#define BASE2 (2 * NE + N_NODES)

// ---------------------------------------------------------------------------
// DPP full-wave (64-lane) sum, result broadcast via readlane -> SGPR.
// Sequence: row_shr 1/2/4/8 then row_bcast:15 (rows 1,3) + row_bcast:31
// (rows 2,3); lane 63 holds the total. Pure VALU — no DS pipe.
// ---------------------------------------------------------------------------
__device__ __forceinline__ float wave_sum(float x)
{
    int v = __float_as_int(x);
    int t;
    t = __builtin_amdgcn_update_dpp(0, v, 0x111, 0xf, 0xf, false); // row_shr:1
    v = __float_as_int(__int_as_float(v) + __int_as_float(t));
    t = __builtin_amdgcn_update_dpp(0, v, 0x112, 0xf, 0xf, false); // row_shr:2
    v = __float_as_int(__int_as_float(v) + __int_as_float(t));
    t = __builtin_amdgcn_update_dpp(0, v, 0x114, 0xf, 0xf, false); // row_shr:4
    v = __float_as_int(__int_as_float(v) + __int_as_float(t));
    t = __builtin_amdgcn_update_dpp(0, v, 0x118, 0xf, 0xf, false); // row_shr:8
    v = __float_as_int(__int_as_float(v) + __int_as_float(t));
    t = __builtin_amdgcn_update_dpp(0, v, 0x142, 0xa, 0xf, false); // row_bcast:15
    v = __float_as_int(__int_as_float(v) + __int_as_float(t));
    t = __builtin_amdgcn_update_dpp(0, v, 0x143, 0xc, 0xf, false); // row_bcast:31
    v = __float_as_int(__int_as_float(v) + __int_as_float(t));
    return __int_as_float(__builtin_amdgcn_readlane(v, 63));
}

// ---------------------------------------------------------------------------
// GEMM: Y[N,512] = x[N,256] @ [Wl | Wr] + [bl | br]
// 128x128 tile, 256 threads, 8x8 micro-tile (cols split tx*4 and 64+tx*4).
// ---------------------------------------------------------------------------
__global__ __launch_bounds__(256) void gemm_xlr(
    const float* __restrict__ x, const float* __restrict__ Wl,
    const float* __restrict__ Wr, const float* __restrict__ bl,
    const float* __restrict__ br, float* __restrict__ Y)
{
    __shared__ float As[16][132];   // [k][m], pad 132 -> 2-way max on writes
    __shared__ float Bs[16][132];   // [k][n]
    const int row0 = blockIdx.x * 128;
    const int col0 = blockIdx.y * 128;            // 0,128,256,384
    const float* B    = (col0 < 256) ? Wl : Wr;
    const float* bias = (col0 < 256) ? bl : br;
    const int bcol0   = (col0 < 256) ? col0 : (col0 - 256);

    const int t  = threadIdx.x;
    const int ty = t >> 4;   // 0..15
    const int tx = t & 15;   // 0..15

    float acc[8][8] = {};

    for (int k0 = 0; k0 < FDIM; k0 += 16) {
#pragma unroll
        for (int i = 0; i < 2; ++i) {           // A: 128 rows x 16 k
            int idx = t + 256 * i;              // 0..511
            int r   = idx >> 2;                 // 0..127
            int q   = idx & 3;                  // float4 slot along k
            float4 av = {0.f, 0.f, 0.f, 0.f};
            if (row0 + r < N_NODES)
                av = *(const float4*)(x + (size_t)(row0 + r) * FDIM + k0 + q * 4);
            As[q * 4 + 0][r] = av.x;
            As[q * 4 + 1][r] = av.y;
            As[q * 4 + 2][r] = av.z;
            As[q * 4 + 3][r] = av.w;
        }
#pragma unroll
        for (int i = 0; i < 2; ++i) {           // B: 16 k x 128 cols
            int idx = t + 256 * i;
            int kr  = idx >> 5;                 // 0..15
            int cc  = (idx & 31) * 4;           // 0..124
            *(float4*)&Bs[kr][cc] =
                *(const float4*)(B + (size_t)(k0 + kr) * 256 + bcol0 + cc);
        }
        __syncthreads();
#pragma unroll
        for (int k = 0; k < 16; ++k) {
            float af[8], bf[8];
            *(float4*)&af[0] = *(const float4*)&As[k][ty * 8];
            *(float4*)&af[4] = *(const float4*)&As[k][ty * 8 + 4];
            *(float4*)&bf[0] = *(const float4*)&Bs[k][tx * 4];
            *(float4*)&bf[4] = *(const float4*)&Bs[k][64 + tx * 4];
#pragma unroll
            for (int i2 = 0; i2 < 8; ++i2)
#pragma unroll
                for (int j2 = 0; j2 < 8; ++j2)
                    acc[i2][j2] = fmaf(af[i2], bf[j2], acc[i2][j2]);
        }
        __syncthreads();
    }

    float4 blo = *(const float4*)(bias + bcol0 + tx * 4);
    float4 bhi = *(const float4*)(bias + bcol0 + 64 + tx * 4);
#pragma unroll
    for (int i2 = 0; i2 < 8; ++i2) {
        int r = row0 + ty * 8 + i2;
        if (r < N_NODES) {
            float4 o1, o2;
            o1.x = acc[i2][0] + blo.x; o1.y = acc[i2][1] + blo.y;
            o1.z = acc[i2][2] + blo.z; o1.w = acc[i2][3] + blo.w;
            o2.x = acc[i2][4] + bhi.x; o2.y = acc[i2][5] + bhi.y;
            o2.z = acc[i2][6] + bhi.z; o2.w = acc[i2][7] + bhi.w;
            *(float4*)&Y[(size_t)r * 512 + col0 + tx * 4]      = o1;
            *(float4*)&Y[(size_t)r * 512 + col0 + 64 + tx * 4] = o2;
        }
    }
}

// ---------------------------------------------------------------------------
// Gating: gate[n][k] = softmax(x[n] @ Wg + bg). One wave per node.
// ---------------------------------------------------------------------------
__global__ __launch_bounds__(256) void gate_kernel(
    const float* __restrict__ x, const float* __restrict__ Wg,
    const float* __restrict__ bg, float* __restrict__ gate)
{
    const int n    = (blockIdx.x * blockDim.x + threadIdx.x) >> 6;
    const int lane = threadIdx.x & 63;
    if (n >= N_NODES) return;
    const float* xrow = x + (size_t)n * FDIM;
    float p0 = 0.f, p1 = 0.f, p2 = 0.f;
#pragma unroll
    for (int q = 0; q < 4; ++q) {
        int f = q * 64 + lane;
        float xv = xrow[f];
        p0 = fmaf(xv, Wg[f * 3 + 0], p0);
        p1 = fmaf(xv, Wg[f * 3 + 1], p1);
        p2 = fmaf(xv, Wg[f * 3 + 2], p2);
    }
    p0 = wave_sum(p0); p1 = wave_sum(p1); p2 = wave_sum(p2);
    float g0 = p0 + bg[0], g1 = p1 + bg[1], g2 = p2 + bg[2];
    float mg = fmaxf(g0, fmaxf(g1, g2));
    g0 = exp2f((g0 - mg) * LOG2E);
    g1 = exp2f((g1 - mg) * LOG2E);
    g2 = exp2f((g2 - mg) * LOG2E);
    float inv = 1.f / (g0 + g1 + g2);
    if (lane == 0) {
        gate[n * 3 + 0] = g0 * inv;
        gate[n * 3 + 1] = g1 * inv;
        gate[n * 3 + 2] = g2 * inv;
    }
}

// ---------------------------------------------------------------------------
// CSR build: histogram -> scan (per hop) -> scatter
// ---------------------------------------------------------------------------
__device__ __forceinline__ void decode_edge(int i, const int* e0, const int* e1,
                                            const int* e2, int& k, int& src,
                                            int& dst)
{
    if (i < NE) {
        k = 0; src = e0[i]; dst = e0[NE + i];
    } else if (i < NE + N_NODES) {
        k = 0; src = i - NE; dst = src;          // hop-0 self loop
    } else if (i < 2 * NE + N_NODES) {
        int j = i - (NE + N_NODES);
        k = 1; src = e1[j]; dst = e1[NE + j];
    } else {
        int j = i - (2 * NE + N_NODES);
        k = 2; src = e2[j]; dst = e2[NE + j];
    }
}

__global__ void hist_kernel(const int* __restrict__ e0,
                            const int* __restrict__ e1,
                            const int* __restrict__ e2, int* __restrict__ cnt)
{
    for (int i = blockIdx.x * blockDim.x + threadIdx.x; i < TOT_EDGES;
         i += gridDim.x * blockDim.x) {
        int k, src, dst;
        decode_edge(i, e0, e1, e2, k, src, dst);
        atomicAdd(&cnt[k * N_NODES + dst], 1);
    }
}

// 3 blocks (one per hop) x 1024 threads; wave-shuffle scan, 3 barriers/chunk.
__global__ __launch_bounds__(1024) void scan_kernel(const int* __restrict__ cnt,
                                                    int* __restrict__ off,
                                                    int* __restrict__ cursor)
{
    const int k = blockIdx.x;
    const int* c = cnt + k * N_NODES;
    int* o   = off + (size_t)k * (N_NODES + 1);
    int* cur = cursor + k * N_NODES;
    __shared__ int wsum[16];
    __shared__ int s_carry;
    const int lane = threadIdx.x & 63;
    const int wid  = threadIdx.x >> 6;
    if (threadIdx.x == 0) s_carry = 0;
    __syncthreads();
    for (int base = 0; base < N_NODES; base += 1024) {
        int i  = base + threadIdx.x;
        int v0 = (i < N_NODES) ? c[i] : 0;
        int v  = v0;
#pragma unroll
        for (int s = 1; s < 64; s <<= 1) {
            int t2 = __shfl_up(v, s);
            if (lane >= s) v += t2;
        }
        if (lane == 63) wsum[wid] = v;
        __syncthreads();
        if (wid == 0) {
            int ws = (lane < 16) ? wsum[lane] : 0;
#pragma unroll
            for (int s = 1; s < 16; s <<= 1) {
                int t2 = __shfl_up(ws, s);
                if (lane >= s) ws += t2;
            }
            if (lane < 16) wsum[lane] = ws;   // inclusive wave sums
        }
        __syncthreads();
        int carry = s_carry;
        int wexcl = (wid > 0) ? wsum[wid - 1] : 0;
        int excl  = carry + wexcl + (v - v0);
        if (i < N_NODES) { o[i] = excl; cur[i] = excl; }
        __syncthreads();
        if (threadIdx.x == 1023) s_carry = carry + wsum[15];
        __syncthreads();
    }
    if (threadIdx.x == 0) o[N_NODES] = s_carry;
}

__global__ void scatter_kernel(const int* __restrict__ e0,
                               const int* __restrict__ e1,
                               const int* __restrict__ e2,
                               int* __restrict__ cursor,
                               int* __restrict__ srcs)
{
    for (int i = blockIdx.x * blockDim.x + threadIdx.x; i < TOT_EDGES;
         i += gridDim.x * blockDim.x) {
        int k, src, dst;
        decode_edge(i, e0, e1, e2, k, src, dst);
        int pos = atomicAdd(&cursor[k * N_NODES + dst], 1);
        int base = (k == 0) ? BASE0 : (k == 1) ? BASE1 : BASE2;
        srcs[base + pos] = src;
    }
}

// ---------------------------------------------------------------------------
// Aggregation: one wave per destination node; lane = channel (C == 64).
// No-max softmax (exp2 with log2e folded into att), DPP reductions,
// chunked src prefetch + 1-deep gather pipeline.
// ---------------------------------------------------------------------------
__global__ __launch_bounds__(256) void aggregate_kernel(
    const float* __restrict__ XLR,      // [N,512] = [xl | xr]
    const float* __restrict__ gate,     // [N,3]
    const int* __restrict__ off,        // [3][N+1]
    const int* __restrict__ srcs,       // [TOT_EDGES]
    const float* __restrict__ att,      // [3,4,64]
    const float* __restrict__ bias_out, // [3,64]
    float* __restrict__ out)            // [N,64]
{
    const int n    = (blockIdx.x * blockDim.x + threadIdx.x) >> 6;
    const int lane = threadIdx.x & 63;
    if (n >= N_NODES) return;

    const float* xrr = XLR + (size_t)n * 512 + 256;
    const float xr0 = xrr[lane];
    const float xr1 = xrr[64 + lane];
    const float xr2 = xrr[128 + lane];
    const float xr3 = xrr[192 + lane];

    float o_acc = 0.f;

#pragma unroll
    for (int k = 0; k < NK; ++k) {
        const float a0 = att[(k * 4 + 0) * 64 + lane] * LOG2E;
        const float a1 = att[(k * 4 + 1) * 64 + lane] * LOG2E;
        const float a2 = att[(k * 4 + 2) * 64 + lane] * LOG2E;
        const float a3 = att[(k * 4 + 3) * 64 + lane] * LOG2E;
        const int jb = off[k * (N_NODES + 1) + n];
        const int je = off[k * (N_NODES + 1) + n + 1];
        const int base = (k == 0) ? BASE0 : (k == 1) ? BASE1 : BASE2;
        const int cntk = je - jb;

        float l0 = 0.f, l1 = 0.f, l2 = 0.f, l3 = 0.f;
        float c0 = 0.f, c1 = 0.f, c2 = 0.f, c3 = 0.f;

        if (cntk > 0) {
            int sv = srcs[base + min(jb + lane, je - 1)];
            int src = __builtin_amdgcn_readlane(sv, 0);
            const float* r = XLR + (size_t)src * 512;
            float v0 = r[lane], v1 = r[64 + lane];
            float v2 = r[128 + lane], v3 = r[192 + lane];

            for (int u = 0; u < cntk; ++u) {
                float w0 = v0, w1 = v1, w2 = v2, w3 = v3;
                int un = u + 1;
                if (un < cntk) {
                    if ((un & 63) == 0)
                        sv = srcs[base + min(jb + un + lane, je - 1)];
                    int s2 = __builtin_amdgcn_readlane(sv, un & 63);
                    const float* r2 = XLR + (size_t)s2 * 512;
                    v0 = r2[lane];       v1 = r2[64 + lane];
                    v2 = r2[128 + lane]; v3 = r2[192 + lane];
                }

                float e0 = w0 + xr0; e0 = (e0 > 0.f) ? e0 : NEG_SLOPE * e0;
                float e1 = w1 + xr1; e1 = (e1 > 0.f) ? e1 : NEG_SLOPE * e1;
                float e2 = w2 + xr2; e2 = (e2 > 0.f) ? e2 : NEG_SLOPE * e2;
                float e3 = w3 + xr3; e3 = (e3 > 0.f) ? e3 : NEG_SLOPE * e3;

                float s0 = wave_sum(e0 * a0);
                float s1 = wave_sum(e1 * a1);
                float s2_ = wave_sum(e2 * a2);
                float s3 = wave_sum(e3 * a3);

                float ee0 = exp2f(s0), ee1 = exp2f(s1);
                float ee2 = exp2f(s2_), ee3 = exp2f(s3);

                l0 += ee0; c0 = fmaf(ee0, w0, c0);
                l1 += ee1; c1 = fmaf(ee1, w1, c1);
                l2 += ee2; c2 = fmaf(ee2, w2, c2);
                l3 += ee3; c3 = fmaf(ee3, w3, c3);
            }
        }

        float msg = 0.f;
        if (cntk > 0)
            msg = 0.25f * (c0 / l0 + c1 / l1 + c2 / l2 + c3 / l3);
        o_acc = fmaf(gate[n * 3 + k], msg + bias_out[k * 64 + lane], o_acc);
    }

    out[(size_t)n * 64 + lane] = o_acc;
}

// ---------------------------------------------------------------------------
extern "C" void kernel_launch(void* const* d_in, const int* in_sizes, int n_in,
                              void* d_out, int out_size, void* d_ws,
                              size_t ws_size, hipStream_t stream)
{
    const float* x        = (const float*)d_in[0];
    const int*   e0       = (const int*)d_in[1];
    const int*   e1       = (const int*)d_in[2];
    const int*   e2       = (const int*)d_in[3];
    const float* Wl       = (const float*)d_in[4];
    const float* bl       = (const float*)d_in[5];
    const float* Wr       = (const float*)d_in[6];
    const float* br       = (const float*)d_in[7];
    const float* att      = (const float*)d_in[8];
    const float* bias_out = (const float*)d_in[9];
    const float* Wg       = (const float*)d_in[10];
    const float* bg       = (const float*)d_in[11];
    float* out = (float*)d_out;

    char* wsb = (char*)d_ws;
    float* XLR = (float*)wsb;                       // N*512 f32
    size_t o = (size_t)N_NODES * 512 * sizeof(float);
    int* cnt    = (int*)(wsb + o); o += (size_t)3 * N_NODES * sizeof(int);
    int* off    = (int*)(wsb + o); o += (size_t)3 * (N_NODES + 1) * sizeof(int);
    int* cursor = (int*)(wsb + o); o += (size_t)3 * N_NODES * sizeof(int);
    int* srcs   = (int*)(wsb + o); o += (size_t)TOT_EDGES * sizeof(int);
    float* gate = (float*)(wsb + o); o += (size_t)N_NODES * 3 * sizeof(float);

    hipMemsetAsync(cnt, 0, (size_t)3 * N_NODES * sizeof(int), stream);

    dim3 ggrid((N_NODES + 127) / 128, 4);
    gemm_xlr<<<ggrid, 256, 0, stream>>>(x, Wl, Wr, bl, br, XLR);

    gate_kernel<<<(N_NODES * 64 + 255) / 256, 256, 0, stream>>>(x, Wg, bg, gate);

    int eblocks = (TOT_EDGES + 255) / 256;
    hist_kernel<<<eblocks, 256, 0, stream>>>(e0, e1, e2, cnt);
    scan_kernel<<<3, 1024, 0, stream>>>(cnt, off, cursor);
    scatter_kernel<<<eblocks, 256, 0, stream>>>(e0, e1, e2, cursor, srcs);

    int ablocks = (N_NODES * 64 + 255) / 256;
    aggregate_kernel<<<ablocks, 256, 0, stream>>>(XLR, gate, off, srcs, att,
                                                  bias_out, out);
}

// Round 3
// 365.647 us; speedup vs baseline: 1.6686x; 1.2522x over previous
//
#include <hip/hip_runtime.h>

#define N_NODES 20000
#define FDIM    256
#define NE      400000
#define NH      4
#define NC      64
#define NK      3
#define LOG2E   1.44269504088896340736f

// Virtual edge stream: [hop0 real E][hop0 self-loops N][hop1 E][hop2 E]
#define TOT_EDGES (3 * NE + N_NODES)
#define NSEG      (3 * N_NODES)             // CSR segments, global across hops
#define NCHUNK    ((NSEG + 1023) / 1024)    // 59

// ---------------------------------------------------------------------------
// Full-wave (64-lane) sum via DPP row_shr + row_bcast; result broadcast.
// ---------------------------------------------------------------------------
__device__ __forceinline__ float wave_sum(float x)
{
    int v = __float_as_int(x);
    int t;
    t = __builtin_amdgcn_update_dpp(0, v, 0x111, 0xf, 0xf, false); // row_shr:1
    v = __float_as_int(__int_as_float(v) + __int_as_float(t));
    t = __builtin_amdgcn_update_dpp(0, v, 0x112, 0xf, 0xf, false); // row_shr:2
    v = __float_as_int(__int_as_float(v) + __int_as_float(t));
    t = __builtin_amdgcn_update_dpp(0, v, 0x114, 0xf, 0xf, false); // row_shr:4
    v = __float_as_int(__int_as_float(v) + __int_as_float(t));
    t = __builtin_amdgcn_update_dpp(0, v, 0x118, 0xf, 0xf, false); // row_shr:8
    v = __float_as_int(__int_as_float(v) + __int_as_float(t));
    t = __builtin_amdgcn_update_dpp(0, v, 0x142, 0xa, 0xf, false); // row_bcast:15
    v = __float_as_int(__int_as_float(v) + __int_as_float(t));
    t = __builtin_amdgcn_update_dpp(0, v, 0x143, 0xc, 0xf, false); // row_bcast:31
    v = __float_as_int(__int_as_float(v) + __int_as_float(t));
    return __int_as_float(__builtin_amdgcn_readlane(v, 63));
}

// Sum within each 16-lane row via DPP row_ror rotation butterfly.
// Every lane of a row ends with that row's total (self-broadcasting).
__device__ __forceinline__ float rowsum16(float x)
{
    int v = __float_as_int(x);
    int t;
    t = __builtin_amdgcn_update_dpp(0, v, 0x121, 0xf, 0xf, false); // row_ror:1
    v = __float_as_int(__int_as_float(v) + __int_as_float(t));
    t = __builtin_amdgcn_update_dpp(0, v, 0x122, 0xf, 0xf, false); // row_ror:2
    v = __float_as_int(__int_as_float(v) + __int_as_float(t));
    t = __builtin_amdgcn_update_dpp(0, v, 0x124, 0xf, 0xf, false); // row_ror:4
    v = __float_as_int(__int_as_float(v) + __int_as_float(t));
    t = __builtin_amdgcn_update_dpp(0, v, 0x128, 0xf, 0xf, false); // row_ror:8
    v = __float_as_int(__int_as_float(v) + __int_as_float(t));
    return __int_as_float(v);
}

// ---------------------------------------------------------------------------
// GEMM: XL[N,256] = x @ Wl + bl ; XR[N,256] = x @ Wr + br
// 128x128 tile, 256 threads, 8x8 micro-tile.
// ---------------------------------------------------------------------------
__global__ __launch_bounds__(256) void gemm_xlr(
    const float* __restrict__ x, const float* __restrict__ Wl,
    const float* __restrict__ Wr, const float* __restrict__ bl,
    const float* __restrict__ br, float* __restrict__ XL,
    float* __restrict__ XR)
{
    __shared__ float As[16][132];
    __shared__ float Bs[16][132];
    const int row0 = blockIdx.x * 128;
    const int col0 = blockIdx.y * 128;            // 0,128,256,384
    const float* B    = (col0 < 256) ? Wl : Wr;
    const float* bias = (col0 < 256) ? bl : br;
    float* Yk         = (col0 < 256) ? XL : XR;
    const int bcol0   = (col0 < 256) ? col0 : (col0 - 256);

    const int t  = threadIdx.x;
    const int ty = t >> 4;   // 0..15
    const int tx = t & 15;   // 0..15

    float acc[8][8] = {};

    for (int k0 = 0; k0 < FDIM; k0 += 16) {
#pragma unroll
        for (int i = 0; i < 2; ++i) {           // A: 128 rows x 16 k
            int idx = t + 256 * i;
            int r   = idx >> 2;
            int q   = idx & 3;
            float4 av = {0.f, 0.f, 0.f, 0.f};
            if (row0 + r < N_NODES)
                av = *(const float4*)(x + (size_t)(row0 + r) * FDIM + k0 + q * 4);
            As[q * 4 + 0][r] = av.x;
            As[q * 4 + 1][r] = av.y;
            As[q * 4 + 2][r] = av.z;
            As[q * 4 + 3][r] = av.w;
        }
#pragma unroll
        for (int i = 0; i < 2; ++i) {           // B: 16 k x 128 cols
            int idx = t + 256 * i;
            int kr  = idx >> 5;
            int cc  = (idx & 31) * 4;
            *(float4*)&Bs[kr][cc] =
                *(const float4*)(B + (size_t)(k0 + kr) * 256 + bcol0 + cc);
        }
        __syncthreads();
#pragma unroll
        for (int k = 0; k < 16; ++k) {
            float af[8], bf[8];
            *(float4*)&af[0] = *(const float4*)&As[k][ty * 8];
            *(float4*)&af[4] = *(const float4*)&As[k][ty * 8 + 4];
            *(float4*)&bf[0] = *(const float4*)&Bs[k][tx * 4];
            *(float4*)&bf[4] = *(const float4*)&Bs[k][64 + tx * 4];
#pragma unroll
            for (int i2 = 0; i2 < 8; ++i2)
#pragma unroll
                for (int j2 = 0; j2 < 8; ++j2)
                    acc[i2][j2] = fmaf(af[i2], bf[j2], acc[i2][j2]);
        }
        __syncthreads();
    }

    float4 blo = *(const float4*)(bias + bcol0 + tx * 4);
    float4 bhi = *(const float4*)(bias + bcol0 + 64 + tx * 4);
#pragma unroll
    for (int i2 = 0; i2 < 8; ++i2) {
        int r = row0 + ty * 8 + i2;
        if (r < N_NODES) {
            float4 o1, o2;
            o1.x = acc[i2][0] + blo.x; o1.y = acc[i2][1] + blo.y;
            o1.z = acc[i2][2] + blo.z; o1.w = acc[i2][3] + blo.w;
            o2.x = acc[i2][4] + bhi.x; o2.y = acc[i2][5] + bhi.y;
            o2.z = acc[i2][6] + bhi.z; o2.w = acc[i2][7] + bhi.w;
            *(float4*)&Yk[(size_t)r * 256 + bcol0 + tx * 4]      = o1;
            *(float4*)&Yk[(size_t)r * 256 + bcol0 + 64 + tx * 4] = o2;
        }
    }
}

// ---------------------------------------------------------------------------
// Gating: gate[n][k] = softmax(x[n] @ Wg + bg). One wave per node.
// ---------------------------------------------------------------------------
__global__ __launch_bounds__(256) void gate_kernel(
    const float* __restrict__ x, const float* __restrict__ Wg,
    const float* __restrict__ bg, float* __restrict__ gate)
{
    const int n    = (blockIdx.x * blockDim.x + threadIdx.x) >> 6;
    const int lane = threadIdx.x & 63;
    if (n >= N_NODES) return;
    const float* xrow = x + (size_t)n * FDIM;
    float p0 = 0.f, p1 = 0.f, p2 = 0.f;
#pragma unroll
    for (int q = 0; q < 4; ++q) {
        int f = q * 64 + lane;
        float xv = xrow[f];
        p0 = fmaf(xv, Wg[f * 3 + 0], p0);
        p1 = fmaf(xv, Wg[f * 3 + 1], p1);
        p2 = fmaf(xv, Wg[f * 3 + 2], p2);
    }
    p0 = wave_sum(p0); p1 = wave_sum(p1); p2 = wave_sum(p2);
    float g0 = p0 + bg[0], g1 = p1 + bg[1], g2 = p2 + bg[2];
    float mg = fmaxf(g0, fmaxf(g1, g2));
    g0 = exp2f((g0 - mg) * LOG2E);
    g1 = exp2f((g1 - mg) * LOG2E);
    g2 = exp2f((g2 - mg) * LOG2E);
    float inv = 1.f / (g0 + g1 + g2);
    if (lane == 0) {
        gate[n * 3 + 0] = g0 * inv;
        gate[n * 3 + 1] = g1 * inv;
        gate[n * 3 + 2] = g2 * inv;
    }
}

// ---------------------------------------------------------------------------
// CSR build (global segment index seg = k*N + dst over all 3 hops)
// ---------------------------------------------------------------------------
__device__ __forceinline__ void decode_edge(int i, const int* e0, const int* e1,
                                            const int* e2, int& k, int& src,
                                            int& dst)
{
    if (i < NE) {
        k = 0; src = e0[i]; dst = e0[NE + i];
    } else if (i < NE + N_NODES) {
        k = 0; src = i - NE; dst = src;          // hop-0 self loop
    } else if (i < 2 * NE + N_NODES) {
        int j = i - (NE + N_NODES);
        k = 1; src = e1[j]; dst = e1[NE + j];
    } else {
        int j = i - (2 * NE + N_NODES);
        k = 2; src = e2[j]; dst = e2[NE + j];
    }
}

__global__ void hist_kernel(const int* __restrict__ e0,
                            const int* __restrict__ e1,
                            const int* __restrict__ e2, int* __restrict__ cnt)
{
    for (int i = blockIdx.x * blockDim.x + threadIdx.x; i < TOT_EDGES;
         i += gridDim.x * blockDim.x) {
        int k, src, dst;
        decode_edge(i, e0, e1, e2, k, src, dst);
        atomicAdd(&cnt[k * N_NODES + dst], 1);
    }
}

// two-level scan over NSEG counts: pass1 block sums, pass2 scan sums, pass3 apply
__global__ __launch_bounds__(1024) void scan_pass1(const int* __restrict__ cnt,
                                                   int* __restrict__ bsum)
{
    int i = blockIdx.x * 1024 + threadIdx.x;
    int v = (i < NSEG) ? cnt[i] : 0;
#pragma unroll
    for (int s = 32; s >= 1; s >>= 1) v += __shfl_xor(v, s);
    if ((threadIdx.x & 63) == 0) atomicAdd(&bsum[blockIdx.x], v);
}

__global__ __launch_bounds__(64) void scan_pass2(const int* __restrict__ bsum,
                                                 int* __restrict__ boff,
                                                 int* __restrict__ goff)
{
    int lane = threadIdx.x;
    int v = (lane < NCHUNK) ? bsum[lane] : 0;
    int incl = v;
#pragma unroll
    for (int s = 1; s < 64; s <<= 1) {
        int t = __shfl_up(incl, s);
        if (lane >= s) incl += t;
    }
    if (lane < NCHUNK) boff[lane] = incl - v;
    if (lane == NCHUNK - 1) goff[NSEG] = incl;   // == TOT_EDGES
}

__global__ __launch_bounds__(1024) void scan_pass3(const int* __restrict__ cnt,
                                                   const int* __restrict__ boff,
                                                   int* __restrict__ goff,
                                                   int* __restrict__ cursor)
{
    __shared__ int wsum[16];
    int i    = blockIdx.x * 1024 + threadIdx.x;
    int lane = threadIdx.x & 63;
    int wid  = threadIdx.x >> 6;
    int v0 = (i < NSEG) ? cnt[i] : 0;
    int v  = v0;
#pragma unroll
    for (int s = 1; s < 64; s <<= 1) {
        int t = __shfl_up(v, s);
        if (lane >= s) v += t;
    }
    if (lane == 63) wsum[wid] = v;
    __syncthreads();
    if (wid == 0) {
        int ws = (lane < 16) ? wsum[lane] : 0;
#pragma unroll
        for (int s = 1; s < 16; s <<= 1) {
            int t = __shfl_up(ws, s);
            if (lane >= s) ws += t;
        }
        if (lane < 16) wsum[lane] = ws;
    }
    __syncthreads();
    int excl = boff[blockIdx.x] + ((wid > 0) ? wsum[wid - 1] : 0) + (v - v0);
    if (i < NSEG) { goff[i] = excl; cursor[i] = excl; }
}

__global__ void scatter_kernel(const int* __restrict__ e0,
                               const int* __restrict__ e1,
                               const int* __restrict__ e2,
                               int* __restrict__ cursor,
                               int* __restrict__ srcs)
{
    for (int i = blockIdx.x * blockDim.x + threadIdx.x; i < TOT_EDGES;
         i += gridDim.x * blockDim.x) {
        int k, src, dst;
        decode_edge(i, e0, e1, e2, k, src, dst);
        int pos = atomicAdd(&cursor[k * N_NODES + dst], 1);
        srcs[pos] = src;
    }
}

// ---------------------------------------------------------------------------
// Aggregation: one wave per node. lane = h*16 + m owns channels 4m..4m+3 of
// head h  ->  float4 at row + 4*lane (contiguous). rowsum16 reduces all 4
// head scores at once; one exp per edge; 4-deep gather pipeline.
// ---------------------------------------------------------------------------
__global__ __launch_bounds__(256) void aggregate_kernel(
    const float* __restrict__ XL,       // [N,256]
    const float* __restrict__ XR,       // [N,256]
    const float* __restrict__ gate,     // [N,3]
    const int* __restrict__ goff,       // [NSEG+1]
    const int* __restrict__ srcs,       // [TOT_EDGES]
    const float* __restrict__ att,      // [3,4,64]
    const float* __restrict__ bias_out, // [3,64]
    float* __restrict__ out)            // [N,64]
{
    const int n    = (blockIdx.x * blockDim.x + threadIdx.x) >> 6;
    const int lane = threadIdx.x & 63;
    if (n >= N_NODES) return;
    const int lof = lane << 2;               // float offset within a 256-row
    const int m4  = (lane & 15) << 2;        // channel block

    const float4 xr = *(const float4*)(XR + ((size_t)n << 8) + lof);

    float o0 = 0.f, o1 = 0.f, o2 = 0.f, o3 = 0.f;
    float bb0 = 0.f, bb1 = 0.f, bb2 = 0.f, bb3 = 0.f;

#pragma unroll
    for (int k = 0; k < NK; ++k) {
        float4 a = *(const float4*)(att + (k << 8) + lof);
        a.x *= LOG2E; a.y *= LOG2E; a.z *= LOG2E; a.w *= LOG2E;
        const float gk = gate[n * 3 + k];
        const float4 b4 = *(const float4*)(bias_out + (k << 6) + m4);
        bb0 = fmaf(gk, b4.x, bb0); bb1 = fmaf(gk, b4.y, bb1);
        bb2 = fmaf(gk, b4.z, bb2); bb3 = fmaf(gk, b4.w, bb3);

        const int jb = goff[k * N_NODES + n];
        const int je = goff[k * N_NODES + n + 1];
        const int cntk = je - jb;
        if (cntk <= 0) continue;
        const int je1 = je - 1;

        float den = 0.f, c0 = 0.f, c1 = 0.f, c2 = 0.f, c3 = 0.f;

        int sv = srcs[min(jb + lane, je1)];
        float4 w0, w1, w2, w3;
        {
            int s_;
            s_ = __builtin_amdgcn_readlane(sv, 0);
            w0 = *(const float4*)(XL + ((size_t)s_ << 8) + lof);
            s_ = __builtin_amdgcn_readlane(sv, min(1, cntk - 1));
            w1 = *(const float4*)(XL + ((size_t)s_ << 8) + lof);
            s_ = __builtin_amdgcn_readlane(sv, min(2, cntk - 1));
            w2 = *(const float4*)(XL + ((size_t)s_ << 8) + lof);
            s_ = __builtin_amdgcn_readlane(sv, min(3, cntk - 1));
            w3 = *(const float4*)(XL + ((size_t)s_ << 8) + lof);
        }

#define STEP(W, UU)                                                           \
        {                                                                     \
            float z0 = W.x + xr.x, z1 = W.y + xr.y;                           \
            float z2 = W.z + xr.z, z3 = W.w + xr.w;                           \
            float e0 = fmaf(0.4f, fabsf(z0), 0.6f * z0);                      \
            float e1 = fmaf(0.4f, fabsf(z1), 0.6f * z1);                      \
            float e2 = fmaf(0.4f, fabsf(z2), 0.6f * z2);                      \
            float e3 = fmaf(0.4f, fabsf(z3), 0.6f * z3);                      \
            float p = fmaf(e3, a.w, fmaf(e2, a.z, fmaf(e1, a.y, e0 * a.x)));  \
            p = rowsum16(p);                                                  \
            float ee = exp2f(p);                                              \
            ee = ((UU) < cntk) ? ee : 0.f;                                    \
            den += ee;                                                        \
            c0 = fmaf(ee, W.x, c0); c1 = fmaf(ee, W.y, c1);                   \
            c2 = fmaf(ee, W.z, c2); c3 = fmaf(ee, W.w, c3);                   \
            int pf = (UU) + 4;                                                \
            if (pf < cntk) {                                                  \
                if ((pf & 63) == 0) sv = srcs[min(jb + pf + lane, je1)];      \
                int s_ = __builtin_amdgcn_readlane(sv, pf & 63);              \
                W = *(const float4*)(XL + ((size_t)s_ << 8) + lof);           \
            }                                                                 \
        }

        for (int u = 0; u < cntk; u += 4) {
            STEP(w0, u);
            STEP(w1, u + 1);
            STEP(w2, u + 2);
            STEP(w3, u + 3);
        }
#undef STEP

        const float s25 = 0.25f * gk / den;
        o0 = fmaf(c0, s25, o0); o1 = fmaf(c1, s25, o1);
        o2 = fmaf(c2, s25, o2); o3 = fmaf(c3, s25, o3);
    }

    // mean over heads: sum the 4 rows (lanes l, l^16, l^32, l^48)
    o0 += __shfl_xor(o0, 16); o0 += __shfl_xor(o0, 32);
    o1 += __shfl_xor(o1, 16); o1 += __shfl_xor(o1, 32);
    o2 += __shfl_xor(o2, 16); o2 += __shfl_xor(o2, 32);
    o3 += __shfl_xor(o3, 16); o3 += __shfl_xor(o3, 32);

    if (lane < 16) {
        float4 r;
        r.x = o0 + bb0; r.y = o1 + bb1; r.z = o2 + bb2; r.w = o3 + bb3;
        *(float4*)(out + ((size_t)n << 6) + m4) = r;
    }
}

// ---------------------------------------------------------------------------
extern "C" void kernel_launch(void* const* d_in, const int* in_sizes, int n_in,
                              void* d_out, int out_size, void* d_ws,
                              size_t ws_size, hipStream_t stream)
{
    const float* x        = (const float*)d_in[0];
    const int*   e0       = (const int*)d_in[1];
    const int*   e1       = (const int*)d_in[2];
    const int*   e2       = (const int*)d_in[3];
    const float* Wl       = (const float*)d_in[4];
    const float* bl       = (const float*)d_in[5];
    const float* Wr       = (const float*)d_in[6];
    const float* br       = (const float*)d_in[7];
    const float* att      = (const float*)d_in[8];
    const float* bias_out = (const float*)d_in[9];
    const float* Wg       = (const float*)d_in[10];
    const float* bg       = (const float*)d_in[11];
    float* out = (float*)d_out;

    char* wsb = (char*)d_ws;
    size_t o = 0;
    float* XL   = (float*)(wsb + o); o += (size_t)N_NODES * 256 * sizeof(float);
    float* XR   = (float*)(wsb + o); o += (size_t)N_NODES * 256 * sizeof(float);
    int* cnt    = (int*)(wsb + o);   o += (size_t)NSEG * sizeof(int);
    int* bsum   = (int*)(wsb + o);   o += 64 * sizeof(int);
    int* boff   = (int*)(wsb + o);   o += 64 * sizeof(int);
    int* goff   = (int*)(wsb + o);   o += (size_t)(NSEG + 1) * sizeof(int);
    int* cursor = (int*)(wsb + o);   o += (size_t)NSEG * sizeof(int);
    int* srcs   = (int*)(wsb + o);   o += (size_t)TOT_EDGES * sizeof(int);
    float* gate = (float*)(wsb + o); o += (size_t)N_NODES * 3 * sizeof(float);

    // zero cnt + bsum (contiguous)
    hipMemsetAsync(cnt, 0, ((size_t)NSEG + 64) * sizeof(int), stream);

    dim3 ggrid((N_NODES + 127) / 128, 4);
    gemm_xlr<<<ggrid, 256, 0, stream>>>(x, Wl, Wr, bl, br, XL, XR);

    gate_kernel<<<(N_NODES * 64 + 255) / 256, 256, 0, stream>>>(x, Wg, bg, gate);

    int eblocks = (TOT_EDGES + 255) / 256;
    hist_kernel<<<eblocks, 256, 0, stream>>>(e0, e1, e2, cnt);
    scan_pass1<<<NCHUNK, 1024, 0, stream>>>(cnt, bsum);
    scan_pass2<<<1, 64, 0, stream>>>(bsum, boff, goff);
    scan_pass3<<<NCHUNK, 1024, 0, stream>>>(cnt, boff, goff, cursor);
    scatter_kernel<<<eblocks, 256, 0, stream>>>(e0, e1, e2, cursor, srcs);

    int ablocks = (N_NODES * 64 + 255) / 256;
    aggregate_kernel<<<ablocks, 256, 0, stream>>>(XL, XR, gate, goff, srcs,
                                                  att, bias_out, out);
}